// Round 14
// baseline (185.408 us; speedup 1.0000x reference)
//
#include <hip/hip_runtime.h>
#include <hip/hip_bf16.h>

// out[m, f] = sum_e cos(x[m, e] + theta[e & 7]) * W[f, e]
// M = 65536, N = K = 512.  bf16 MFMA GEMM, A = cos(x+theta) fused.
//
// PERSISTENT pipeline, grid = 256 (1/CU nominal), 8 stripes of BM=32.
// Stripe s's K-loop covers stripe s+1's x HBM latency: x loads into regs in
// two halves at kf=0 and kf=8 (16 regs each, half-loop lifetime).
// Between stripes: RAW s_barrier + lgkmcnt(0) ONLY (LDS hazards) -- never
// __syncthreads(), whose vmcnt(0) would drain in-flight loads/stores.
// Post-loop order: barA -> pack h0 -> stores -> pack h1 -> B(0,1) -> barB;
// counted vmcnt keeps stores/B in flight through the packs.
// K-loop = round-13 verbatim (unpinned, fragment-major B 2-ahead 3-buf,
// A ds_read 1-ahead).  Single 32 KB LDS tile.  launch_bounds(512,2): the
// ~140-reg peak CANNOT spill (rounds 6/8/9/10 all died of the 128 cap).

typedef __attribute__((ext_vector_type(8))) short short8;   // 8 x bf16
typedef __attribute__((ext_vector_type(4))) float f32x4;    // MFMA acc frag

static constexpr int KD  = 512;
static constexpr int ND  = 512;
static constexpr int BM  = 32;
static constexpr int NKF = 16;           // K steps of 32
static constexpr int MPB = 256;          // rows per persistent block
static constexpr int NST = MPB / BM;     // 8 stripes

static __device__ __forceinline__ unsigned short f2bf(float f) {
    unsigned int b = __builtin_bit_cast(unsigned int, f);
    b += 0x7FFFu + ((b >> 16) & 1u);
    return (unsigned short)(b >> 16);
}

// cos(2*pi*rev) via v_cos_f32 (input in revolutions, fract range-reduce)
static __device__ __forceinline__ float fast_cos_rev(float rev) {
    float r = __builtin_amdgcn_fractf(rev);
    float c;
    asm("v_cos_f32 %0, %1" : "=v"(c) : "v"(r));
    return c;
}

static __device__ __forceinline__ void lds_barrier() {
    asm volatile("s_waitcnt lgkmcnt(0)" ::: "memory");
    __builtin_amdgcn_s_barrier();
}

// Pack W into MFMA-fragment-major bf16:
//   WbF[((n_blk*16 + kf)*64 + lane)*8 + j] =
//       bf16( W[n_blk*16 + (lane&15)][kf*32 + (lane>>4)*8 + j] )
__global__ void cvt_w_frag(const float* __restrict__ W,
                           unsigned short* __restrict__ WbF) {
    const int i    = blockIdx.x * 256 + threadIdx.x;  // 0..32767 fragments
    const int lane = i & 63;
    const int kf   = (i >> 6) & 15;
    const int nblk = i >> 10;                         // 0..31
    const int row  = nblk * 16 + (lane & 15);         // f index
    const int col  = kf * 32 + (lane >> 4) * 8;       // e index
    const float* p = W + (size_t)row * KD + col;
    float4 w0 = *reinterpret_cast<const float4*>(p);
    float4 w1 = *reinterpret_cast<const float4*>(p + 4);
    short8 t8;
    t8[0] = (short)f2bf(w0.x); t8[1] = (short)f2bf(w0.y);
    t8[2] = (short)f2bf(w0.z); t8[3] = (short)f2bf(w0.w);
    t8[4] = (short)f2bf(w1.x); t8[5] = (short)f2bf(w1.y);
    t8[6] = (short)f2bf(w1.z); t8[7] = (short)f2bf(w1.w);
    *reinterpret_cast<short8*>(WbF + (size_t)i * 8) = t8;
}

template <bool PRECVT>
__global__ __launch_bounds__(512, 2)
void fused_qgemm(const float* __restrict__ x, const float* __restrict__ theta,
                 const float* __restrict__ W, const unsigned short* __restrict__ WbF,
                 float* __restrict__ out) {
    __shared__ unsigned short Alds[BM * KD];   // 32 KB, pitch 1024 B, swizzled

    const int tid  = threadIdx.x;
    const int lane = tid & 63;
    const int wave = tid >> 6;                 // 0..7 -> n0 = wave*64
    const int mb   = blockIdx.x * MPB;

    const int frow = lane & 15;
    const int fkg  = lane >> 4;

    constexpr float INV2PI = 0.15915493667125702f;
    float thC[8];
#pragma unroll
    for (int j = 0; j < 8; ++j) thC[j] = theta[j] * INV2PI;

    // ---- staging map: row = tid>>4 (0..31), chunk c at col (tid&15)*8 + c*128
    const int srow = tid >> 4;
    const int sc0  = (tid & 15) * 8;
    const int swz  = (srow & 7) << 4;
    const float* xrow = x + (size_t)(mb + srow) * KD + sc0;

    float4 xv[4][2];                           // 4 chunks x 8 floats
    auto loadXc = [&](int s, int c) {
        const float* xp = xrow + (size_t)s * BM * KD + c * 128;
        xv[c][0] = *reinterpret_cast<const float4*>(xp);
        xv[c][1] = *reinterpret_cast<const float4*>(xp + 4);
    };
    auto packXc = [&](int c) {
        float v[8];
        *reinterpret_cast<float4*>(&v[0]) = xv[c][0];
        *reinterpret_cast<float4*>(&v[4]) = xv[c][1];
        short8 pk;
#pragma unroll
        for (int j = 0; j < 8; ++j)    // (sc0 + c*128) % 8 == 0 -> theta idx j
            pk[j] = (short)f2bf(fast_cos_rev(__builtin_fmaf(v[j], INV2PI, thC[j])));
        *reinterpret_cast<short8*>(
            reinterpret_cast<char*>(&Alds[0]) + srow * 1024 +
            (((sc0 + c * 128) * 2) ^ swz)) = pk;
    };

    // ---- B: fragment-major base (fully coalesced 16B/lane loads) ----
    const unsigned short* wbase =
        PRECVT ? (WbF + ((size_t)wave * 4096 + lane) * 8) : nullptr;
    const float* wpf[4];
#pragma unroll
    for (int jn = 0; jn < 4; ++jn)
        wpf[jn] = W + (size_t)(wave * 64 + jn * 16 + frow) * KD + fkg * 8;

    auto loadB = [&](int kf, short8* dst) {
#pragma unroll
        for (int jn = 0; jn < 4; ++jn) {
            if (PRECVT) {
                dst[jn] = *reinterpret_cast<const short8*>(
                    wbase + (size_t)(jn * 16 + kf) * 512);
            } else {
                float4 w0 = *reinterpret_cast<const float4*>(wpf[jn] + kf * 32);
                float4 w1 = *reinterpret_cast<const float4*>(wpf[jn] + kf * 32 + 4);
                short8 t8;
                t8[0] = (short)f2bf(w0.x); t8[1] = (short)f2bf(w0.y);
                t8[2] = (short)f2bf(w0.z); t8[3] = (short)f2bf(w0.w);
                t8[4] = (short)f2bf(w1.x); t8[5] = (short)f2bf(w1.y);
                t8[6] = (short)f2bf(w1.z); t8[7] = (short)f2bf(w1.w);
                dst[jn] = t8;
            }
        }
    };

    auto loadA = [&](int kf, short8* dst) {
#pragma unroll
        for (int i = 0; i < 2; ++i) {
            const int row  = i * 16 + frow;
            const int byte = row * 1024 + (((kf * 32 + fkg * 8) * 2) ^ ((row & 7) << 4));
            dst[i] = *reinterpret_cast<const short8*>(
                reinterpret_cast<const char*>(&Alds[0]) + byte);
        }
    };

    short8 bb[3][4];
    short8 aa[2][2];
    f32x4  acc[2][4];
#pragma unroll
    for (int i = 0; i < 2; ++i)
#pragma unroll
        for (int j = 0; j < 4; ++j) acc[i][j] = (f32x4)(0.0f);

    // ---- prologue: stage stripe 0, prefetch B(0),B(1) ----
#pragma unroll
    for (int c = 0; c < 4; ++c) loadXc(0, c);
    loadB(0, bb[0]);
    loadB(1, bb[1]);
#pragma unroll
    for (int c = 0; c < 4; ++c) packXc(c);
    lds_barrier();

#pragma unroll 1
    for (int s = 0; s < NST; ++s) {
        const bool more = (s + 1 < NST);

        loadA(0, aa[0]);
#pragma unroll
        for (int kf = 0; kf < NKF; ++kf) {
            if (kf == 0 && more) { loadXc(s + 1, 0); loadXc(s + 1, 1); }
            if (kf == 8 && more) { loadXc(s + 1, 2); loadXc(s + 1, 3); }
            if (kf + 1 < NKF) loadA(kf + 1, aa[(kf + 1) & 1]);
            if (kf + 2 < NKF) loadB(kf + 2, bb[(kf + 2) % 3]);
#pragma unroll
            for (int i = 0; i < 2; ++i)
#pragma unroll
                for (int jn = 0; jn < 4; ++jn)
                    acc[i][jn] = __builtin_amdgcn_mfma_f32_16x16x32_bf16(
                        bb[kf % 3][jn], aa[kf & 1][i], acc[i][jn], 0, 0, 0);
        }

        if (more) {
            lds_barrier();                 // all waves done reading Alds (barA)
            packXc(0); packXc(1);          // counted vmcnt: waits x only
        }

        // ---- store stripe s (fire-and-forget) ----
        float* op = out + (size_t)(mb + s * BM + frow) * ND + wave * 64 + fkg * 4;
#pragma unroll
        for (int i = 0; i < 2; ++i)
#pragma unroll
            for (int jn = 0; jn < 4; ++jn) {
                *reinterpret_cast<f32x4*>(op + (size_t)(i * 16) * ND + jn * 16) =
                    acc[i][jn];
                acc[i][jn] = (f32x4)(0.0f);
            }

        if (more) {
            packXc(2); packXc(3);
            loadB(0, bb[0]);               // next stripe's B, flies over barB
            loadB(1, bb[1]);
            lds_barrier();                 // Alds writes visible (barB)
        }
    }
}

extern "C" void kernel_launch(void* const* d_in, const int* in_sizes, int n_in,
                              void* d_out, int out_size, void* d_ws, size_t ws_size,
                              hipStream_t stream) {
    const float* x     = (const float*)d_in[0];
    const float* theta = (const float*)d_in[1];
    const float* W     = (const float*)d_in[2];
    float* out         = (float*)d_out;

    const int M      = in_sizes[0] / KD;       // 65536
    const int wElems = in_sizes[2];            // 512*512

    if (ws_size >= (size_t)wElems * sizeof(unsigned short)) {
        unsigned short* WbF = (unsigned short*)d_ws;
        cvt_w_frag<<<wElems / 8 / 256, 256, 0, stream>>>(W, WbF);
        fused_qgemm<true><<<M / MPB, 512, 0, stream>>>(x, theta, W, WbF, out);
    } else {
        fused_qgemm<false><<<M / MPB, 512, 0, stream>>>(x, theta, W, nullptr, out);
    }
}

// Round 15
// 82.096 us; speedup vs baseline: 2.2584x; 2.2584x over previous
//
#include <hip/hip_runtime.h>
#include <hip/hip_bf16.h>

// out[m, f] = sum_e cos(x[m, e] + theta[e & 7]) * W[f, e]
// M = 65536, N = K = 512.  bf16 MFMA GEMM, A = cos(x+theta) fused in staging.
//
// ROUND 15 = ROUND 7 BASE (BM=64, clean, 77us) + two additive fixes:
//  (1) NON-TEMPORAL x loads: the x stream was evicting the L2-resident
//      512 KB W copy -> per-kf B loads paid L3 latency (~500cyc) vs my
//      160cyc prefetch cover.  nt-loads keep B L2-hot.
//  (2) B prefetch 3-ahead (bb[4], +16 VGPR): issue-to-use ~240-320 cyc
//      of MFMA cover, matching L2-hit latency.
// Block = 64x512 stripe (full N -> x read once).  64 KB LDS A-tile staged
// once (XOR-swizzled), ONE barrier, fully-unrolled 16-step K loop,
// fragment-major B (coalesced dwordx4), pins kept (R13: unpinned collapses
// the prefetch), launch_bounds(512,2) (R6's 128-cap spilled at BM=64).

typedef __attribute__((ext_vector_type(8))) short short8;   // 8 x bf16
typedef __attribute__((ext_vector_type(4))) float f32x4;    // MFMA acc frag

static constexpr int KD  = 512;
static constexpr int ND  = 512;
static constexpr int BM  = 64;
static constexpr int NKF = 16;           // K steps of 32

static __device__ __forceinline__ unsigned short f2bf(float f) {
    unsigned int b = __builtin_bit_cast(unsigned int, f);
    b += 0x7FFFu + ((b >> 16) & 1u);
    return (unsigned short)(b >> 16);
}

// cos(2*pi*rev) via v_cos_f32 (input in revolutions, fract range-reduce)
static __device__ __forceinline__ float fast_cos_rev(float rev) {
    float r = __builtin_amdgcn_fractf(rev);
    float c;
    asm("v_cos_f32 %0, %1" : "=v"(c) : "v"(r));
    return c;
}

// Pack W into MFMA-fragment-major bf16:
//   WbF[((n_blk*16 + kf)*64 + lane)*8 + j] =
//       bf16( W[n_blk*16 + (lane&15)][kf*32 + (lane>>4)*8 + j] )
__global__ void cvt_w_frag(const float* __restrict__ W,
                           unsigned short* __restrict__ WbF) {
    const int i    = blockIdx.x * 256 + threadIdx.x;  // 0..32767 fragments
    const int lane = i & 63;
    const int kf   = (i >> 6) & 15;
    const int nblk = i >> 10;                         // 0..31
    const int row  = nblk * 16 + (lane & 15);         // f index
    const int col  = kf * 32 + (lane >> 4) * 8;       // e index
    const float* p = W + (size_t)row * KD + col;
    float4 w0 = *reinterpret_cast<const float4*>(p);
    float4 w1 = *reinterpret_cast<const float4*>(p + 4);
    short8 t8;
    t8[0] = (short)f2bf(w0.x); t8[1] = (short)f2bf(w0.y);
    t8[2] = (short)f2bf(w0.z); t8[3] = (short)f2bf(w0.w);
    t8[4] = (short)f2bf(w1.x); t8[5] = (short)f2bf(w1.y);
    t8[6] = (short)f2bf(w1.z); t8[7] = (short)f2bf(w1.w);
    *reinterpret_cast<short8*>(WbF + (size_t)i * 8) = t8;
}

template <bool PRECVT>
__global__ __launch_bounds__(512, 2)
void fused_qgemm(const float* __restrict__ x, const float* __restrict__ theta,
                 const float* __restrict__ W, const unsigned short* __restrict__ WbF,
                 float* __restrict__ out) {
    __shared__ unsigned short Alds[BM * KD];   // 64 KB, pitch 1024 B, swizzled

    const int tid  = threadIdx.x;
    const int lane = tid & 63;
    const int wave = tid >> 6;                 // 0..7 -> n0 = wave*64
    const int m0   = blockIdx.x * BM;

    const int frow = lane & 15;
    const int fkg  = lane >> 4;

    constexpr float INV2PI = 0.15915493667125702f;
    float thC[8];
#pragma unroll
    for (int j = 0; j < 8; ++j) thC[j] = theta[j] * INV2PI;

    // ---- B: fragment-major base (fully coalesced 16B/lane loads) ----
    const unsigned short* wbase =
        PRECVT ? (WbF + ((size_t)wave * 4096 + lane) * 8) : nullptr;
    const float* wpf[4];
#pragma unroll
    for (int jn = 0; jn < 4; ++jn)
        wpf[jn] = W + (size_t)(wave * 64 + jn * 16 + frow) * KD + fkg * 8;

    auto loadB = [&](int kf, short8* dst) {
#pragma unroll
        for (int jn = 0; jn < 4; ++jn) {
            if (PRECVT) {
                dst[jn] = *reinterpret_cast<const short8*>(
                    wbase + (size_t)(jn * 16 + kf) * 512);
            } else {
                float4 w0 = *reinterpret_cast<const float4*>(wpf[jn] + kf * 32);
                float4 w1 = *reinterpret_cast<const float4*>(wpf[jn] + kf * 32 + 4);
                short8 t8;
                t8[0] = (short)f2bf(w0.x); t8[1] = (short)f2bf(w0.y);
                t8[2] = (short)f2bf(w0.z); t8[3] = (short)f2bf(w0.w);
                t8[4] = (short)f2bf(w1.x); t8[5] = (short)f2bf(w1.y);
                t8[6] = (short)f2bf(w1.z); t8[7] = (short)f2bf(w1.w);
                dst[jn] = t8;
            }
        }
    };

    short8 bb[4][4];                           // 3-ahead rotation
    f32x4  acc[4][4];
#pragma unroll
    for (int i = 0; i < 4; ++i)
#pragma unroll
        for (int j = 0; j < 4; ++j) acc[i][j] = (f32x4)(0.0f);

    // ---- stage A tile: 64 rows x 512 cols; NON-TEMPORAL x loads ----
    {
        const int srow = tid >> 3;             // 0..63
        const int sc0  = (tid & 7) * 8;        // 0..56
        const float* xp = x + (size_t)(m0 + srow) * KD + sc0;
        f32x4 xv[8][2];
#pragma unroll
        for (int c = 0; c < 8; ++c) {
            xv[c][0] = __builtin_nontemporal_load(
                reinterpret_cast<const f32x4*>(xp + c * 64));
            xv[c][1] = __builtin_nontemporal_load(
                reinterpret_cast<const f32x4*>(xp + c * 64 + 4));
        }
        loadB(0, bb[0]);
        loadB(1, bb[1]);
        loadB(2, bb[2]);

        char* lb = reinterpret_cast<char*>(&Alds[0]) + srow * 1024;
        const int swz = (srow & 7) << 4;
#pragma unroll
        for (int c = 0; c < 8; ++c) {
            short8 pk;
#pragma unroll
            for (int j = 0; j < 8; ++j) {  // (sc0 + c*64) % 8 == 0 -> theta idx j
                float v = (j < 4) ? xv[c][0][j] : xv[c][1][j - 4];
                pk[j] = (short)f2bf(fast_cos_rev(__builtin_fmaf(v, INV2PI, thC[j])));
            }
            *reinterpret_cast<short8*>(lb + (((sc0 + c * 64) * 2) ^ swz)) = pk;
        }
    }
    __syncthreads();

    auto loadA = [&](int kf, short8* dst) {
#pragma unroll
        for (int i = 0; i < 4; ++i) {
            const int row  = i * 16 + frow;
            const int byte = row * 1024 + (((kf * 32 + fkg * 8) * 2) ^ ((row & 7) << 4));
            dst[i] = *reinterpret_cast<const short8*>(
                reinterpret_cast<const char*>(&Alds[0]) + byte);
        }
    };

    short8 aa[2][4];
    loadA(0, aa[0]);

    // ---- K loop: loads first, pinned, then MFMA (3-ahead B, 1-ahead A) ----
#pragma unroll
    for (int kf = 0; kf < NKF; ++kf) {
        if (kf + 1 < NKF) loadA(kf + 1, aa[(kf + 1) & 1]);
        if (kf + 3 < NKF) loadB(kf + 3, bb[(kf + 3) & 3]);
        __builtin_amdgcn_sched_barrier(0);
#pragma unroll
        for (int i = 0; i < 4; ++i)
#pragma unroll
            for (int jn = 0; jn < 4; ++jn)
                acc[i][jn] = __builtin_amdgcn_mfma_f32_16x16x32_bf16(
                    bb[kf & 3][jn], aa[kf & 1][i], acc[i][jn], 0, 0, 0);
    }

    // ---- epilogue: m = m0 + i*16 + frow, n = wave*64 + jn*16 + fkg*4 + r ----
    float* op = out + (size_t)(m0 + frow) * ND + wave * 64 + fkg * 4;
#pragma unroll
    for (int i = 0; i < 4; ++i)
#pragma unroll
        for (int jn = 0; jn < 4; ++jn)
            *reinterpret_cast<f32x4*>(op + (size_t)(i * 16) * ND + jn * 16) =
                acc[i][jn];
}

extern "C" void kernel_launch(void* const* d_in, const int* in_sizes, int n_in,
                              void* d_out, int out_size, void* d_ws, size_t ws_size,
                              hipStream_t stream) {
    const float* x     = (const float*)d_in[0];
    const float* theta = (const float*)d_in[1];
    const float* W     = (const float*)d_in[2];
    float* out         = (float*)d_out;

    const int M      = in_sizes[0] / KD;       // 65536
    const int wElems = in_sizes[2];            // 512*512

    if (ws_size >= (size_t)wElems * sizeof(unsigned short)) {
        unsigned short* WbF = (unsigned short*)d_ws;
        cvt_w_frag<<<wElems / 8 / 256, 256, 0, stream>>>(W, WbF);
        fused_qgemm<true><<<M / BM, 512, 0, stream>>>(x, theta, W, WbF, out);
    } else {
        fused_qgemm<false><<<M / BM, 512, 0, stream>>>(x, theta, W, nullptr, out);
    }
}